// Round 8
// baseline (13877.589 us; speedup 1.0000x reference)
//
#include <hip/hip_runtime.h>
#include <hip/hip_bf16.h>
#include <cstdint>
#include <cstddef>

namespace {

constexpr int S_LEN  = 256;
constexpr int BATCH  = 256;
constexpr int NH     = 512;
constexpr int NE     = 256;
constexpr int NSTEPS = 127;          // TGT_LEN-1
constexpr int N1     = 2048;         // [Wo;Wz;Wr;Wn_partial]
constexpr size_t SB        = (size_t)S_LEN * BATCH;   // 65536
constexpr size_t SRC_ELEMS = SB * NH;                 // 33,554,432

typedef __attribute__((ext_vector_type(8))) short  short8v;
typedef __attribute__((ext_vector_type(4))) float  float4v;
typedef unsigned short us;

constexpr int EPI_EPROJ = 1, EPI_S0 = 4;

__device__ __forceinline__ float bf2f(us u) {
  union { unsigned int i; float f; } c; c.i = ((unsigned int)u) << 16; return c.f;
}
__device__ __forceinline__ us f2bf(float f) {
  union { float f; unsigned int i; } c; c.f = f;
  unsigned int x = c.i;
  return (us)((x + 0x7FFFu + ((x >> 16) & 1u)) >> 16);
}
// tanh(x) = 1 - 2/(e^{2x}+1)
__device__ __forceinline__ float tanh2(float x) {
  return 1.f - 2.f * __builtin_amdgcn_rcpf(__expf(2.f * x) + 1.f);
}
__device__ __forceinline__ float sigm(float x) {
  return __builtin_amdgcn_rcpf(1.f + __expf(-x));
}
// one wave stages 1KB: per-lane global addr g (lane*16B apart), uniform LDS dst l
__device__ __forceinline__ void gload16(const us* g, us* l) {
  __builtin_amdgcn_global_load_lds(
      (const __attribute__((address_space(1))) unsigned int*)g,
      (__attribute__((address_space(3))) unsigned int*)l, 16, 0, 0);
}

// ---------------- prologue: conversions ----------------

// src_enc (S,B,H) f32 -> src_t (B,S,H) bf16
__global__ void k_conv_src(const float* __restrict__ src, us* __restrict__ dst) {
  const int total = S_LEN * BATCH * 64;       // 8-elem chunks, dest-linear
  int i = blockIdx.x * blockDim.x + threadIdx.x;
  int stride = gridDim.x * blockDim.x;
  for (; i < total; i += stride) {
    int c = i & 63, s = (i >> 6) & 255, b = i >> 14;
    const float* p = src + ((size_t)s * BATCH + b) * NH + c * 8;
    float4 v0 = *(const float4*)p;
    float4 v1 = *(const float4*)(p + 4);
    us o[8] = { f2bf(v0.x), f2bf(v0.y), f2bf(v0.z), f2bf(v0.w),
                f2bf(v1.x), f2bf(v1.y), f2bf(v1.z), f2bf(v1.w) };
    *(short8v*)(dst + (size_t)i * 8) = *(const short8v*)o;
  }
}

__global__ void k_conv_w(const float* __restrict__ Wo, const float* __restrict__ Wz,
                         const float* __restrict__ Wr, const float* __restrict__ Wn,
                         const float* __restrict__ Wa, const float* __restrict__ Ws,
                         const float* __restrict__ Wob, const float* __restrict__ Wzb,
                         const float* __restrict__ Wrb, const float* __restrict__ Wnb,
                         us* __restrict__ W1cat, us* __restrict__ Wns,
                         us* __restrict__ Was, us* __restrict__ Wae,
                         us* __restrict__ Wsbf, float* __restrict__ bcat) {
  const int T1 = 2048 * 1280;
  const int T2 = 512 * 512;
  const int total = T1 + 4 * T2 + 2048;
  int i = blockIdx.x * blockDim.x + threadIdx.x;
  int stride = gridDim.x * blockDim.x;
  for (; i < total; i += stride) {
    int idx = i;
    if (idx < T1) {
      int row = idx / 1280, col = idx - row * 1280;
      float v;
      if      (row < 512)  v = Wo[row * 1280 + col];
      else if (row < 1024) v = Wz[(row - 512) * 1280 + col];
      else if (row < 1536) v = Wr[(row - 1024) * 1280 + col];
      else {
        int g = row - 1536;
        v = (col >= 256 && col < 768) ? 0.f : Wn[g * 1280 + col];
      }
      W1cat[idx] = f2bf(v);
    } else if ((idx -= T1) < T2) {
      int g = idx >> 9, j = idx & 511;
      Wns[idx] = f2bf(Wn[g * 1280 + 256 + j]);
    } else if ((idx -= T2) < T2) {
      int g = idx >> 9, h = idx & 511;
      Was[idx] = f2bf(Wa[g * 1024 + h]);
    } else if ((idx -= T2) < T2) {
      int g = idx >> 9, h = idx & 511;
      Wae[idx] = f2bf(Wa[g * 1024 + 512 + h]);
    } else if ((idx -= T2) < T2) {
      Wsbf[idx] = f2bf(Ws[idx]);
    } else {
      idx -= T2;
      bcat[idx] = (idx < 512) ? Wob[idx]
                : (idx < 1024) ? Wzb[idx - 512]
                : (idx < 1536) ? Wrb[idx - 1024]
                               : Wnb[idx - 1536];
    }
  }
}

__global__ void k_emb(const int* __restrict__ tgt, const float* __restrict__ table,
                      us* __restrict__ emb) {
  const int total = NSTEPS * BATCH * NE;
  int i = blockIdx.x * blockDim.x + threadIdx.x;
  int stride = gridDim.x * blockDim.x;
  for (; i < total; i += stride) {
    int e  = i & (NE - 1);
    int tb = i >> 8;
    int sym = tgt[tb];
    emb[i] = f2bf(table[sym * NE + e]);
  }
}

// ------------- prologue 8-wave MFMA GEMM tile: 64x128, BK=64 (s0 / eproj) ----------
template<int EPI>
__global__ __launch_bounds__(512, 2) void k_gemm(
    const us* __restrict__ A0, int lda, const us* __restrict__ Bw, int ldb, int K,
    const float* __restrict__ bias, float* __restrict__ f0, us* __restrict__ g0) {
  __shared__ alignas(16) char smem[49152];
  char* As0 = smem;               // 2 x 8192
  char* Bs0 = smem + 16384;       // 2 x 16384
  const int tid = threadIdx.x;
  const int m0 = blockIdx.x * 64, n0 = blockIdx.y * 128;
  const int arow = tid >> 3, ac = (tid & 7) * 8;
  const int brow = tid >> 2, bc = (tid & 3) * 16;
  short8v ar, br0, br1;

  auto loadT = [&](int k0) {
    ar = *(const short8v*)(A0 + (size_t)(m0 + arow) * lda + (k0 + ac));
    const us* q = Bw + (size_t)(n0 + brow) * ldb + (k0 + bc);
    br0 = *(const short8v*)q;
    br1 = *(const short8v*)(q + 8);
  };
  auto stage = [&](int buf) {
    *(short8v*)(As0 + buf * 8192 + arow * 128 + ((ac * 2) ^ ((arow & 7) << 4))) = ar;
    char* bb = Bs0 + buf * 16384 + brow * 128;
    const int sw = (brow & 7) << 4;
    *(short8v*)(bb + ((bc * 2) ^ sw)) = br0;
    *(short8v*)(bb + ((bc * 2 + 16) ^ sw)) = br1;
  };

  const int lane = tid & 63, wave = tid >> 6;
  const int wm = (wave >> 2) * 32, wn = (wave & 3) * 32;
  const int fr = lane & 15, kq = lane >> 4;
  const int ra0 = wm + fr, ra1 = ra0 + 16;
  const int rb0 = wn + fr, rb1 = rb0 + 16;
  float4v acc00 = {0,0,0,0}, acc01 = {0,0,0,0}, acc10 = {0,0,0,0}, acc11 = {0,0,0,0};

  loadT(0);
  stage(0);
  const int nit = K >> 6;
  for (int it = 0; it < nit; ++it) {
    __syncthreads();
    if (it + 1 < nit) loadT((it + 1) << 6);
    const char* ab = As0 + (it & 1) * 8192;
    const char* bb = Bs0 + (it & 1) * 16384;
    #pragma unroll
    for (int ks = 0; ks < 2; ++ks) {
      const int cb = ks * 64 + kq * 16;
      short8v a0 = *(const short8v*)(ab + ra0 * 128 + (cb ^ ((ra0 & 7) << 4)));
      short8v a1 = *(const short8v*)(ab + ra1 * 128 + (cb ^ ((ra1 & 7) << 4)));
      short8v b0 = *(const short8v*)(bb + rb0 * 128 + (cb ^ ((rb0 & 7) << 4)));
      short8v b1 = *(const short8v*)(bb + rb1 * 128 + (cb ^ ((rb1 & 7) << 4)));
      acc00 = __builtin_amdgcn_mfma_f32_16x16x32_bf16(a0, b0, acc00, 0, 0, 0);
      acc01 = __builtin_amdgcn_mfma_f32_16x16x32_bf16(a0, b1, acc01, 0, 0, 0);
      acc10 = __builtin_amdgcn_mfma_f32_16x16x32_bf16(a1, b0, acc10, 0, 0, 0);
      acc11 = __builtin_amdgcn_mfma_f32_16x16x32_bf16(a1, b1, acc11, 0, 0, 0);
    }
    if (it + 1 < nit) stage((it + 1) & 1);
  }

  #pragma unroll
  for (int am = 0; am < 2; ++am) {
    #pragma unroll
    for (int bn = 0; bn < 2; ++bn) {
      float4v a = am ? (bn ? acc11 : acc10) : (bn ? acc01 : acc00);
      #pragma unroll
      for (int r = 0; r < 4; ++r) {
        const int rowO = m0 + wm + am * 16 + kq * 4 + r;
        const int colO = n0 + wn + bn * 16 + fr;
        float v = a[r];
        if (EPI == EPI_S0) {
          float tv = tanh2(v + bias[colO]);
          f0[(size_t)rowO * 512 + colO] = tv;
          g0[(size_t)rowO * 512 + colO] = f2bf(tv);
        } else { // EPI_EPROJ
          g0[(size_t)rowO * 512 + colO] = f2bf(v + bias[colO]);
        }
      }
    }
  }
}

// ---- k_sq: GRU-finish(t-1) via MFMA -> s_t (LDS + global), then q = 2*s@Was^T ----
// grid 16 = (mi = bid>>2) * 64 rows x (ni = bid&3) * 128 q-cols
__global__ __launch_bounds__(512, 1) void k_sq(
    const us* __restrict__ xn, const us* __restrict__ Wns, const us* __restrict__ Was,
    const float* __restrict__ zi, const float* __restrict__ npart,
    float* __restrict__ s_f32, us* __restrict__ s_bf,
    float* __restrict__ dec_st_t, float* __restrict__ qbuf, int has_gru) {
  __shared__ alignas(16) char smem[114688];
  char* sL = smem;                  // 64 rows x 1024B swizzled s-tile (bf16, K=512)
  char* As = smem + 65536;          // 2 x 8192
  char* Bs = smem + 81920;          // 2 x 16384
  const int tid = threadIdx.x;
  const int m0 = (blockIdx.x >> 2) * 64;
  const int ni = blockIdx.x & 3;
  const int lane = tid & 63, wv = tid >> 6;
  const int arow = tid >> 3, ac = (tid & 7) * 8;
  const int brow = tid >> 2, bc = (tid & 3) * 16;
  const int wm = (wv >> 2) * 32, wn = (wv & 3) * 32;
  const int fr = lane & 15, kq = lane >> 4;
  const int ra0 = wm + fr, ra1 = ra0 + 16;
  const int rb0 = wn + fr, rb1 = rb0 + 16;

  short8v arv, brv0, brv1;
  auto loadA1 = [&](int k0) {
    arv = *(const short8v*)(xn + (size_t)(m0 + arow) * 512 + k0 + ac);
  };
  auto loadB = [&](const us* W, int n0, int k0) {
    const us* q = W + (size_t)(n0 + brow) * 512 + k0 + bc;
    brv0 = *(const short8v*)q;
    brv1 = *(const short8v*)(q + 8);
  };
  auto stageA = [&](int buf) {
    *(short8v*)(As + buf * 8192 + arow * 128 + ((ac * 2) ^ ((arow & 7) << 4))) = arv;
  };
  auto stageB = [&](int buf) {
    char* bb = Bs + buf * 16384 + brow * 128;
    const int sw = (brow & 7) << 4;
    *(short8v*)(bb + ((bc * 2) ^ sw)) = brv0;
    *(short8v*)(bb + ((bc * 2 + 16) ^ sw)) = brv1;
  };

  if (has_gru) {
    // GEMM1: acc = xn @ Wns^T over full N; epilogue = GRU finish -> s-tile
    for (int nt = 0; nt < 4; ++nt) {
      const int n0 = nt * 128;
      float4v a00 = {0,0,0,0}, a01 = {0,0,0,0}, a10 = {0,0,0,0}, a11 = {0,0,0,0};
      loadA1(0); loadB(Wns, n0, 0);
      stageA(0); stageB(0);
      for (int kt = 0; kt < 8; ++kt) {
        __syncthreads();
        if (kt + 1 < 8) { loadA1((kt + 1) * 64); loadB(Wns, n0, (kt + 1) * 64); }
        const char* ab = As + (kt & 1) * 8192;
        const char* bb = Bs + (kt & 1) * 16384;
        #pragma unroll
        for (int ks = 0; ks < 2; ++ks) {
          const int cb = ks * 64 + kq * 16;
          short8v a0 = *(const short8v*)(ab + ra0 * 128 + (cb ^ ((ra0 & 7) << 4)));
          short8v a1 = *(const short8v*)(ab + ra1 * 128 + (cb ^ ((ra1 & 7) << 4)));
          short8v b0 = *(const short8v*)(bb + rb0 * 128 + (cb ^ ((rb0 & 7) << 4)));
          short8v b1 = *(const short8v*)(bb + rb1 * 128 + (cb ^ ((rb1 & 7) << 4)));
          a00 = __builtin_amdgcn_mfma_f32_16x16x32_bf16(a0, b0, a00, 0, 0, 0);
          a01 = __builtin_amdgcn_mfma_f32_16x16x32_bf16(a0, b1, a01, 0, 0, 0);
          a10 = __builtin_amdgcn_mfma_f32_16x16x32_bf16(a1, b0, a10, 0, 0, 0);
          a11 = __builtin_amdgcn_mfma_f32_16x16x32_bf16(a1, b1, a11, 0, 0, 0);
        }
        if (kt + 1 < 8) { stageA((kt + 1) & 1); stageB((kt + 1) & 1); }
      }
      #pragma unroll
      for (int am = 0; am < 2; ++am) {
        #pragma unroll
        for (int bn = 0; bn < 2; ++bn) {
          float4v a = am ? (bn ? a11 : a10) : (bn ? a01 : a00);
          #pragma unroll
          for (int r = 0; r < 4; ++r) {
            const int lrow = wm + am * 16 + kq * 4 + r;
            const int colG = n0 + wn + bn * 16 + fr;
            const size_t idx = (size_t)(m0 + lrow) * 512 + colG;
            float nv = tanh2(a[r] + npart[idx]);
            float z  = zi[idx];
            float so = s_f32[idx];
            float sn = (1.f - z) * so + z * nv;
            us snb = f2bf(sn);
            *(us*)(sL + lrow * 1024 + ((2 * colG) ^ ((lrow & 7) << 4))) = snb;
            if (ni == 0) {
              s_f32[idx] = sn;
              s_bf[idx] = snb;
              __builtin_nontemporal_store(sn, &dec_st_t[idx]);
            }
          }
        }
      }
    }
  } else {
    for (int i = tid; i < 64 * 512; i += 512) {
      int r = i >> 9, h2 = i & 511;
      size_t idx = (size_t)(m0 + r) * 512 + h2;
      float v = s_f32[idx];
      *(us*)(sL + r * 1024 + ((2 * h2) ^ ((r & 7) << 4))) = f2bf(v);
      if (ni == 0) __builtin_nontemporal_store(v, &dec_st_t[idx]);
    }
  }
  __syncthreads();

  // GEMM2: qbuf[m0.., ni*128..] = 2 * (s @ Was^T), A from sL
  {
    const int n0 = ni * 128;
    float4v a00 = {0,0,0,0}, a01 = {0,0,0,0}, a10 = {0,0,0,0}, a11 = {0,0,0,0};
    loadB(Was, n0, 0); stageB(0);
    for (int kt = 0; kt < 8; ++kt) {
      __syncthreads();
      if (kt + 1 < 8) loadB(Was, n0, (kt + 1) * 64);
      const char* bb = Bs + (kt & 1) * 16384;
      #pragma unroll
      for (int ks = 0; ks < 2; ++ks) {
        const int cbA = kt * 128 + ks * 64 + kq * 16;      // byte col in s-tile
        const int cbB = ks * 64 + kq * 16;
        short8v a0 = *(const short8v*)(sL + ra0 * 1024 + (cbA ^ ((ra0 & 7) << 4)));
        short8v a1 = *(const short8v*)(sL + ra1 * 1024 + (cbA ^ ((ra1 & 7) << 4)));
        short8v b0 = *(const short8v*)(bb + rb0 * 128 + (cbB ^ ((rb0 & 7) << 4)));
        short8v b1 = *(const short8v*)(bb + rb1 * 128 + (cbB ^ ((rb1 & 7) << 4)));
        a00 = __builtin_amdgcn_mfma_f32_16x16x32_bf16(a0, b0, a00, 0, 0, 0);
        a01 = __builtin_amdgcn_mfma_f32_16x16x32_bf16(a0, b1, a01, 0, 0, 0);
        a10 = __builtin_amdgcn_mfma_f32_16x16x32_bf16(a1, b0, a10, 0, 0, 0);
        a11 = __builtin_amdgcn_mfma_f32_16x16x32_bf16(a1, b1, a11, 0, 0, 0);
      }
      if (kt + 1 < 8) stageB((kt + 1) & 1);
    }
    #pragma unroll
    for (int am = 0; am < 2; ++am) {
      #pragma unroll
      for (int bn = 0; bn < 2; ++bn) {
        float4v a = am ? (bn ? a11 : a10) : (bn ? a01 : a00);
        #pragma unroll
        for (int r = 0; r < 4; ++r) {
          const int lrow = wm + am * 16 + kq * 4 + r;
          const int colG = n0 + wn + bn * 16 + fr;
          qbuf[(size_t)(m0 + lrow) * 512 + colG] = 2.f * a[r];
        }
      }
    }
  }
}

// ---- k_attn: half-panel scores + max-free softmax partials + ci partials ----
// grid 512 = (b = bid>>1) x (c = bid&1: rows c*128..c*128+127)
__global__ __launch_bounds__(256, 2) void k_attn(
    const us* __restrict__ ep, const us* __restrict__ src,
    const float* __restrict__ qbuf, const float* __restrict__ vaw,
    const int* __restrict__ slen,
    float* __restrict__ pbuf,     // (B,256) unnormalized p
    float* __restrict__ lsbuf,    // (B,2) partial sums
    float* __restrict__ cpart) {  // (2,B,512) f32 ci partials
  __shared__ alignas(16) us stg[3][16][512];   // 48KB
  __shared__ float pl[128];
  __shared__ float lred[4];
  __shared__ float wpart[4][512];              // 8KB
  const int bid = blockIdx.x, tid = threadIdx.x;
  const int b = bid >> 1, c = bid & 1;
  const int lane = tid & 63, wv = tid >> 6;    // 4 waves
  const int g0l = lane * 8;
  const int len = slen[b];
  const int s0 = c * 128;
  const us* epb  = ep  + ((size_t)b * S_LEN + s0) * NH;
  const us* srcb = src + ((size_t)b * S_LEN + s0) * NH;

  float vv2[8]; float sumv = 0.f;
  {
    const float* vp = vaw + g0l;
    #pragma unroll
    for (int j = 0; j < 8; j++) { vv2[j] = 2.f * vp[j]; sumv += vp[j]; }
    #pragma unroll
    for (int off = 32; off > 0; off >>= 1) sumv += __shfl_xor(sumv, off, 64);
  }
  float q2[8];
  {
    const float* qp = qbuf + b * 512 + g0l;
    #pragma unroll
    for (int j = 0; j < 8; j++) q2[j] = qp[j];
  }

  auto issue = [&](const us* base, int chunk, int buf) {
    #pragma unroll
    for (int i = 0; i < 4; ++i) {
      int r = wv * 4 + i;
      gload16(base + (size_t)(chunk * 16 + r) * NH + g0l, &stg[buf][r][0]);
    }
  };

  // ---- scores + exp over this half (8 chunks of 16 rows) ----
  issue(epb, 0, 0); issue(epb, 1, 1); issue(epb, 2, 2);
  float lsum = 0.f;
  #pragma unroll
  for (int ch = 0; ch < 8; ++ch) {
    if (ch < 6)       asm volatile("s_waitcnt vmcnt(8)" ::: "memory");
    else if (ch == 6) asm volatile("s_waitcnt vmcnt(4)" ::: "memory");
    else              asm volatile("s_waitcnt vmcnt(0)" ::: "memory");
    #pragma unroll
    for (int i = 0; i < 4; ++i) {
      const int r = wv * 4 + i;
      const int s = ch * 16 + r;
      short8v v = *(const short8v*)&stg[ch % 3][r][g0l];
      float acc = 0.f;
      #pragma unroll
      for (int j = 0; j < 8; j++) {
        float arg = __builtin_fmaf(bf2f((us)v[j]), 2.f, q2[j]);
        acc = __builtin_fmaf(vv2[j], __builtin_amdgcn_rcpf(__expf(arg) + 1.f), acc);
      }
      #pragma unroll
      for (int off = 32; off > 0; off >>= 1) acc += __shfl_xor(acc, off, 64);
      float p = (s0 + s < len) ? __expf(sumv - acc) : 0.f;
      if (lane == 0) pl[s] = p;
      lsum += p;
    }
    asm volatile("s_waitcnt lgkmcnt(0)" ::: "memory");
    __builtin_amdgcn_sched_barrier(0);
    if (ch + 3 < 8) issue(epb, ch + 3, (ch + 3) % 3);
  }
  if (lane == 0) lred[wv] = lsum;
  __syncthreads();
  float l = lred[0] + lred[1] + lred[2] + lred[3];
  if (tid == 0) lsbuf[b * 2 + c] = l;
  if (tid < 128) pbuf[b * 256 + s0 + tid] = pl[tid];

  // ---- ci partials ----
  issue(srcb, 0, 0); issue(srcb, 1, 1); issue(srcb, 2, 2);
  float a8[8] = {0,0,0,0,0,0,0,0};
  #pragma unroll
  for (int ch = 0; ch < 8; ++ch) {
    if (ch < 6)       asm volatile("s_waitcnt vmcnt(8)" ::: "memory");
    else if (ch == 6) asm volatile("s_waitcnt vmcnt(4)" ::: "memory");
    else              asm volatile("s_waitcnt vmcnt(0)" ::: "memory");
    #pragma unroll
    for (int i = 0; i < 4; ++i) {
      const int r = wv * 4 + i;
      const int s = ch * 16 + r;
      short8v v = *(const short8v*)&stg[ch % 3][r][g0l];
      float pv = pl[s];
      #pragma unroll
      for (int j = 0; j < 8; j++)
        a8[j] = __builtin_fmaf(pv, bf2f((us)v[j]), a8[j]);
    }
    asm volatile("s_waitcnt lgkmcnt(0)" ::: "memory");
    __builtin_amdgcn_sched_barrier(0);
    if (ch + 3 < 8) issue(srcb, ch + 3, (ch + 3) % 3);
  }
  #pragma unroll
  for (int j = 0; j < 8; j++) wpart[wv][g0l + j] = a8[j];
  __syncthreads();
  #pragma unroll
  for (int rep = 0; rep < 2; rep++) {
    int hh = tid + rep * 256;
    float cp = wpart[0][hh] + wpart[1][hh] + wpart[2][hh] + wpart[3][hh];
    cpart[((size_t)c * 256 + b) * 512 + hh] = cp;
  }
}

// -------- k_step1: Y = [emb|s|ci] @ W1cat^T + bcat; blocks 64..71 = attn combine ---
__global__ __launch_bounds__(256, 4) void k_step1(
    const us* __restrict__ emb_t, const us* __restrict__ sbf,
    const us* __restrict__ W1cat, const float* __restrict__ bcat,
    const float* __restrict__ s_f32,
    const float* __restrict__ cpart, const float* __restrict__ lsbuf,
    const float* __restrict__ pbuf,
    float* __restrict__ dec_out_t, float* __restrict__ zi,
    float* __restrict__ npart, us* __restrict__ xn,
    float* __restrict__ dec_at_t) {
  const int bid = blockIdx.x, tid = threadIdx.x;
  if (bid >= 64) {
    // attn normalize + write
    const int bb0 = (bid - 64) * 32;
    for (int k = 0; k < 32; ++k) {
      const int b = bb0 + k;
      float inv = __builtin_amdgcn_rcpf(lsbuf[2 * b] + lsbuf[2 * b + 1]);
      __builtin_nontemporal_store(pbuf[b * 256 + tid] * inv,
                                  &dec_at_t[b * 256 + tid]);
    }
    return;
  }
  __shared__ alignas(16) char smem[24576];
  const int lane = tid & 63, wv = tid >> 6;
  char* As = smem;            // 64 x 128B
  char* Bs = smem + 8192;     // 128 x 128B
  const int m0 = (bid >> 4) * 64, n0 = (bid & 15) * 128;
  const int fr = lane & 15, kq = lane >> 4;
  const int wm = (wv & 1) * 32, wn0 = (wv >> 1) * 32;
  const int ra0 = wm + fr, ra1 = ra0 + 16;
  float4v acc[2][2][2];
  #pragma unroll
  for (int x = 0; x < 2; x++)
    #pragma unroll
    for (int y = 0; y < 2; y++)
      #pragma unroll
      for (int z = 0; z < 2; z++) acc[x][y][z] = (float4v){0,0,0,0};

  for (int kt = 0; kt < 20; ++kt) {
    __syncthreads();
    #pragma unroll
    for (int j = 0; j < 2; j++) {
      int cid = tid + 256 * j;
      int arow = cid >> 3, ac8 = (cid & 7) * 8;
      int cc = kt * 64 + ac8, rowg = m0 + arow;
      short8v av;
      if (cc < 256) {
        av = *(const short8v*)(emb_t + (size_t)rowg * 256 + cc);
      } else if (cc < 768) {
        av = *(const short8v*)(sbf + (size_t)rowg * 512 + (cc - 256));
      } else {
        const int jj = cc - 768;
        float inv = __builtin_amdgcn_rcpf(lsbuf[2 * rowg] + lsbuf[2 * rowg + 1]);
        const float* q0 = cpart + (size_t)rowg * 512 + jj;
        const float* q1 = cpart + (size_t)(256 + rowg) * 512 + jj;
        float4 u0 = *(const float4*)q0, u1 = *(const float4*)(q0 + 4);
        float4 w0 = *(const float4*)q1, w1 = *(const float4*)(q1 + 4);
        us o[8] = { f2bf((u0.x + w0.x) * inv), f2bf((u0.y + w0.y) * inv),
                    f2bf((u0.z + w0.z) * inv), f2bf((u0.w + w0.w) * inv),
                    f2bf((u1.x + w1.x) * inv), f2bf((u1.y + w1.y) * inv),
                    f2bf((u1.z + w1.z) * inv), f2bf((u1.w + w1.w) * inv) };
        av = *(const short8v*)o;
      }
      *(short8v*)(As + arow * 128 + ((ac8 * 2) ^ ((arow & 7) << 4))) = av;
    }
    #pragma unroll
    for (int j = 0; j < 4; j++) {
      int cid = tid + 256 * j;
      int brow = cid >> 3, bc8 = (cid & 7) * 8;
      *(short8v*)(Bs + brow * 128 + ((bc8 * 2) ^ ((brow & 7) << 4))) =
          *(const short8v*)(W1cat + (size_t)(n0 + brow) * 1280 + kt * 64 + bc8);
    }
    __syncthreads();
    #pragma unroll
    for (int ks = 0; ks < 2; ++ks) {
      const int cb = ks * 64 + kq * 16;
      short8v a0 = *(const short8v*)(As + ra0 * 128 + (cb ^ ((ra0 & 7) << 4)));
      short8v a1 = *(const short8v*)(As + ra1 * 128 + (cb ^ ((ra1 & 7) << 4)));
      #pragma unroll
      for (int nh = 0; nh < 2; ++nh) {
        const int rb0 = wn0 + nh * 64 + fr, rb1 = rb0 + 16;
        short8v b0 = *(const short8v*)(Bs + rb0 * 128 + (cb ^ ((rb0 & 7) << 4)));
        short8v b1 = *(const short8v*)(Bs + rb1 * 128 + (cb ^ ((rb1 & 7) << 4)));
        acc[nh][0][0] = __builtin_amdgcn_mfma_f32_16x16x32_bf16(a0, b0, acc[nh][0][0], 0, 0, 0);
        acc[nh][0][1] = __builtin_amdgcn_mfma_f32_16x16x32_bf16(a0, b1, acc[nh][0][1], 0, 0, 0);
        acc[nh][1][0] = __builtin_amdgcn_mfma_f32_16x16x32_bf16(a1, b0, acc[nh][1][0], 0, 0, 0);
        acc[nh][1][1] = __builtin_amdgcn_mfma_f32_16x16x32_bf16(a1, b1, acc[nh][1][1], 0, 0, 0);
      }
    }
  }

  #pragma unroll
  for (int nh = 0; nh < 2; ++nh) {
    #pragma unroll
    for (int am = 0; am < 2; ++am) {
      #pragma unroll
      for (int bn = 0; bn < 2; ++bn) {
        #pragma unroll
        for (int r = 0; r < 4; ++r) {
          const int rowO = m0 + wm + am * 16 + kq * 4 + r;
          const int colO = n0 + wn0 + nh * 64 + bn * 16 + fr;
          float v = acc[nh][am][bn][r] + bcat[colO];
          const int qd = colO >> 9, j = colO & 511;
          const size_t idx = (size_t)rowO * 512 + j;
          if      (qd == 0) __builtin_nontemporal_store(v, &dec_out_t[idx]);
          else if (qd == 1) zi[idx] = sigm(v);
          else if (qd == 2) xn[idx] = f2bf(sigm(v) * s_f32[idx]);
          else              npart[idx] = v;
        }
      }
    }
  }
}

} // namespace

extern "C" void kernel_launch(void* const* d_in, const int* in_sizes, int n_in,
                              void* d_out, int out_size, void* d_ws, size_t ws_size,
                              hipStream_t stream) {
  const float* src_enc  = (const float*)d_in[0];
  const int*   tgt      = (const int*)d_in[1];
  const int*   slen     = (const int*)d_in[2];
  const float* emb_tab  = (const float*)d_in[3];
  const float* Wsw      = (const float*)d_in[4];
  const float* Wsb      = (const float*)d_in[5];
  const float* Wzw      = (const float*)d_in[6];
  const float* Wzb      = (const float*)d_in[7];
  const float* Wrw      = (const float*)d_in[8];
  const float* Wrb      = (const float*)d_in[9];
  const float* Wnw      = (const float*)d_in[10];
  const float* Wnb      = (const float*)d_in[11];
  const float* Waw      = (const float*)d_in[12];
  const float* Wab      = (const float*)d_in[13];
  const float* vaw      = (const float*)d_in[14];
  const float* Wow      = (const float*)d_in[15];
  const float* Wob      = (const float*)d_in[16];

  char* ws = (char*)d_ws;
  size_t off = 0;
  auto alloc = [&](size_t bytes) -> void* {
    void* p = ws + off;
    off = (off + bytes + 255) & ~(size_t)255;
    return p;
  };
  us*    src_t  = (us*)alloc(SRC_ELEMS * 2);
  us*    ep_t   = (us*)alloc(SRC_ELEMS * 2);
  us*    emb_bf = (us*)alloc((size_t)NSTEPS * BATCH * NE * 2);
  us*    W1cat  = (us*)alloc((size_t)N1 * 1280 * 2);
  us*    Wns    = (us*)alloc((size_t)512 * 512 * 2);
  us*    Was    = (us*)alloc((size_t)512 * 512 * 2);
  us*    Wae    = (us*)alloc((size_t)512 * 512 * 2);
  us*    Wsbf   = (us*)alloc((size_t)512 * 512 * 2);
  float* bcat   = (float*)alloc((size_t)N1 * 4);
  float* s_f32  = (float*)alloc((size_t)BATCH * NH * 4);
  us*    s_bf   = (us*)alloc((size_t)BATCH * NH * 2);
  float* qbuf   = (float*)alloc((size_t)BATCH * NH * 4);
  float* zi     = (float*)alloc((size_t)BATCH * NH * 4);
  float* npart  = (float*)alloc((size_t)BATCH * NH * 4);
  us*    xn_bf  = (us*)alloc((size_t)BATCH * NH * 2);
  float* pbuf   = (float*)alloc((size_t)BATCH * S_LEN * 4);
  float* lsbuf  = (float*)alloc((size_t)BATCH * 2 * 4);
  float* cpart  = (float*)alloc((size_t)2 * BATCH * NH * 4);

  float* out         = (float*)d_out;
  float* dec_outputs = out;
  float* dec_states  = out + (size_t)NSTEPS * BATCH * NH;
  float* dec_attns   = dec_states + (size_t)NSTEPS * BATCH * NH;

  // ---- prologue ----
  k_conv_src<<<4096, 256, 0, stream>>>(src_enc, src_t);
  k_conv_w<<<2048, 256, 0, stream>>>(Wow, Wzw, Wrw, Wnw, Waw, Wsw,
                                     Wob, Wzb, Wrb, Wnb,
                                     W1cat, Wns, Was, Wae, Wsbf, bcat);
  k_emb<<<2048, 256, 0, stream>>>(tgt, emb_tab, emb_bf);
  // s0 = tanh(src_enc[0] @ Ws^T + Ws_b): src_t rows (b, s=0) at stride S*NH
  k_gemm<EPI_S0><<<dim3(4, 4), 512, 0, stream>>>(
      src_t, S_LEN * NH, Wsbf, 512, 512, Wsb, s_f32, s_bf);
  // ep_t[b,s] = src_t[b,s] @ Wae^T + Wa_b
  k_gemm<EPI_EPROJ><<<dim3(1024, 4), 512, 0, stream>>>(
      src_t, 512, Wae, 512, 512, Wab, nullptr, ep_t);

  // ---- 127 steps x 3 kernels ----
  for (int t = 0; t < NSTEPS; t++) {
    k_sq<<<16, 512, 0, stream>>>(
        xn_bf, Wns, Was, zi, npart, s_f32, s_bf,
        dec_states + (size_t)t * BATCH * NH, qbuf, t > 0 ? 1 : 0);
    k_attn<<<512, 256, 0, stream>>>(
        ep_t, src_t, qbuf, vaw, slen, pbuf, lsbuf, cpart);
    k_step1<<<72, 256, 0, stream>>>(
        emb_bf + (size_t)t * BATCH * NE, s_bf, W1cat, bcat, s_f32,
        cpart, lsbuf, pbuf,
        dec_outputs + (size_t)t * BATCH * NH, zi, npart, xn_bf,
        dec_attns + (size_t)t * BATCH * S_LEN);
  }
}